// Round 10
// baseline (300.330 us; speedup 1.0000x reference)
//
#include <hip/hip_runtime.h>
#include <hip/hip_fp16.h>

#define N_NODES 50000
#define N_EDGES 800000
#define E_TOT   850000   // N_EDGES + N_NODES self loops
#define HC 128
#define NEG_SLOPE 0.2f
#define TILE 128         // per-wave LDS edge tile (deg>TILE uses slow exact fallback)
#define KP 40            // MFMA LDS k-pitch (bf16 elems): 32 + 8 pad
#define CH 4096                              // edges per sort chunk
#define NCH ((E_TOT + CH - 1) / CH)          // 208 chunks  (< 256 required)
#define NP  ((N_NODES + 255) >> 8)           // 196 partitions of 256 dsts (< 256 required)

typedef unsigned short u16;
typedef __attribute__((ext_vector_type(8))) short short8;
typedef __attribute__((ext_vector_type(4))) float f32x4;

// ---------------- helpers ----------------
__device__ __forceinline__ int edge_get(const void* eidx, int f64, long long i) {
  return f64 ? (int)((const long long*)eidx)[i] : ((const int*)eidx)[i];
}
__device__ __forceinline__ float selh(float4 q, int head) {
  float a = (head & 1) ? q.y : q.x;
  float b = (head & 1) ? q.w : q.z;
  return (head & 2) ? b : a;
}
__device__ __forceinline__ float h2f(unsigned short u) {
  __half_raw r; r.x = u;
  return __half2float((__half)r);
}
__device__ __forceinline__ float4 alpha4(float4 as, float4 ad, float w, float4 c) {
  float4 r;
  r.x = as.x + ad.x + w * c.x; r.x = r.x > 0.f ? r.x : NEG_SLOPE * r.x;
  r.y = as.y + ad.y + w * c.y; r.y = r.y > 0.f ? r.y : NEG_SLOPE * r.y;
  r.z = as.z + ad.z + w * c.z; r.z = r.z > 0.f ? r.z : NEG_SLOPE * r.z;
  r.w = as.w + ad.w + w * c.w; r.w = r.w > 0.f ? r.w : NEG_SLOPE * r.w;
  return r;
}
__device__ __forceinline__ void wave_max4(float4& m) {
  #pragma unroll
  for (int o = 1; o < 64; o <<= 1) {
    m.x = fmaxf(m.x, __shfl_xor(m.x, o, 64));
    m.y = fmaxf(m.y, __shfl_xor(m.y, o, 64));
    m.z = fmaxf(m.z, __shfl_xor(m.z, o, 64));
    m.w = fmaxf(m.w, __shfl_xor(m.w, o, 64));
  }
}
__device__ __forceinline__ void wave_sum4(float4& s) {
  #pragma unroll
  for (int o = 1; o < 64; o <<= 1) {
    s.x += __shfl_xor(s.x, o, 64);
    s.y += __shfl_xor(s.y, o, 64);
    s.z += __shfl_xor(s.z, o, 64);
    s.w += __shfl_xor(s.w, o, 64);
  }
}
__device__ __forceinline__ void splitbf(float v, u16& h, u16& l) {
  unsigned b = __float_as_uint(v);
  h = (u16)(b >> 16);
  float lo = v - __uint_as_float(b & 0xFFFF0000u);
  l = (u16)(__float_as_uint(lo) >> 16);
}
// 256-thread block exclusive scan (4 waves).
__device__ __forceinline__ int block_scan_excl(int val, int* lds) {
  int lane = threadIdx.x & 63, wv = threadIdx.x >> 6;
  int inc = val;
  #pragma unroll
  for (int off = 1; off < 64; off <<= 1) {
    int t = __shfl_up(inc, off, 64);
    if (lane >= off) inc += t;
  }
  if (lane == 63) lds[wv] = inc;
  __syncthreads();
  if (threadIdx.x == 0) {
    int s = 0;
    #pragma unroll
    for (int i = 0; i < 4; ++i) { int t = lds[i]; lds[i] = s; s += t; }
  }
  __syncthreads();
  return lds[wv] + inc - val;
}
// block-local int64/int32 probe (wave 0 ballot), result broadcast via LDS
__device__ __forceinline__ int local_detect(const void* eidx, int* f_sh) {
  int tid = threadIdx.x;
  if (tid < 64) {
    long long v = ((const long long*)eidx)[tid];
    int bad = (v < 0 || v >= N_NODES);
    unsigned long long anybad = __ballot(bad);
    if (tid == 0) *f_sh = (anybad == 0ull);
  }
  __syncthreads();
  return *f_sh;
}

// ---- CSR build, pass A: per-chunk partition histogram (LDS only) + ew sum ----
// scal layout (floats): [0]=sum(ew) [1]=mean [4..7]=c1 [8..11]=c2
__global__ __launch_bounds__(256) void chunkhist_kernel(const void* eidx,
    const float* __restrict__ ew, int* __restrict__ cnt, float* __restrict__ scal) {
  __shared__ int hist[NP];
  __shared__ float sh[4];
  __shared__ int f_sh;
  int c = blockIdx.x, tid = threadIdx.x;
  for (int i = tid; i < NP; i += 256) hist[i] = 0;
  int f = local_detect(eidx, &f_sh);   // includes a __syncthreads after hist init
  int i0 = c * CH, i1 = min(i0 + CH, E_TOT);
  float s = 0.f;
  for (int i = i0 + tid; i < i1; i += 256) {
    int d = (i < N_EDGES) ? edge_get(eidx, f, (long long)N_EDGES + i) : (i - N_EDGES);
    atomicAdd(&hist[d >> 8], 1);
    if (i < N_EDGES) s += ew[i];
  }
  #pragma unroll
  for (int m = 32; m >= 1; m >>= 1) s += __shfl_xor(s, m, 64);
  int lane = tid & 63, wv = tid >> 6;
  if (lane == 0) sh[wv] = s;
  __syncthreads();
  for (int i = tid; i < NP; i += 256) cnt[c * NP + i] = hist[i];
  if (tid == 0) atomicAdd(&scal[0], sh[0] + sh[1] + sh[2] + sh[3]);
}

// ---- pass B1: per-partition column scan over chunks ----
__global__ __launch_bounds__(256) void colscan_kernel(const int* __restrict__ cnt,
    int* __restrict__ base_rel, int* __restrict__ ptot) {
  __shared__ int lds[4];
  int p = blockIdx.x, c = threadIdx.x;
  int v = (c < NCH) ? cnt[c * NP + p] : 0;
  int e = block_scan_excl(v, lds);
  if (c < NCH) base_rel[c * NP + p] = e;
  if (c == 255) ptot[p] = e;
}

// ---- pass B2: scan partition totals -> pofs; fold in prep constants ----
__global__ __launch_bounds__(256) void pscan_prep_kernel(const int* __restrict__ ptot,
    int* __restrict__ pofs, const float* __restrict__ We1, const float* __restrict__ ae1,
    const float* __restrict__ We2, const float* __restrict__ ae2,
    float* __restrict__ scal, float inv_e) {
  __shared__ int lds[4];
  int t = threadIdx.x;
  int v = (t < NP) ? ptot[t] : 0;
  int e = block_scan_excl(v, lds);
  if (t <= NP) pofs[t] = e;
  float p = (t < 128) ? We1[t] * ae1[t] : We2[t - 128] * ae2[t - 128];
  #pragma unroll
  for (int m = 16; m >= 1; m >>= 1) p += __shfl_xor(p, m, 32);
  if ((t & 31) == 0) {
    int hd = (t & 127) >> 5;
    if (t < 128) scal[4 + hd] = p; else scal[8 + hd] = p;
  }
  if (t == 0) scal[1] = scal[0] * inv_e;
}

// ---- pass C: partition edges (block-exclusive contiguous runs per partition) ----
// record: x = (dst<<16)|src  (N_NODES<65536), y = bits(w)
__global__ __launch_bounds__(256) void partition_kernel(const void* eidx,
    const float* __restrict__ ew, const float* __restrict__ scal,
    const int* __restrict__ base_rel, const int* __restrict__ pofs,
    int2* __restrict__ swp1) {
  __shared__ int cur[NP];
  __shared__ int f_sh;
  int c = blockIdx.x, tid = threadIdx.x;
  for (int i = tid; i < NP; i += 256) cur[i] = base_rel[c * NP + i] + pofs[i];
  int f = local_detect(eidx, &f_sh);
  float wmean = scal[1];
  int i0 = c * CH, i1 = min(i0 + CH, E_TOT);
  for (int i = i0 + tid; i < i1; i += 256) {
    int s, d; float w;
    if (i < N_EDGES) {
      s = edge_get(eidx, f, i);
      d = edge_get(eidx, f, (long long)N_EDGES + i);
      w = ew[i];
    } else {
      s = d = i - N_EDGES;
      w = wmean;
    }
    int pos = atomicAdd(&cur[d >> 8], 1);
    swp1[pos] = make_int2((int)(((unsigned)d << 16) | (unsigned)s), __float_as_int(w));
  }
}

// ---- pass D: per-partition local counting sort (one block per partition) ----
__global__ __launch_bounds__(256) void localsort_kernel(const int2* __restrict__ swp1,
    const int* __restrict__ pofs, int* __restrict__ offs, int2* __restrict__ swp2) {
  __shared__ int lhist[256];
  __shared__ int lds[4];
  int p = blockIdx.x, tid = threadIdx.x;
  int r0 = pofs[p], r1 = pofs[p + 1];
  lhist[tid] = 0;
  __syncthreads();
  for (int i = r0 + tid; i < r1; i += 256) {
    unsigned key = (unsigned)swp1[i].x;
    atomicAdd(&lhist[(key >> 16) & 255u], 1);
  }
  __syncthreads();
  int v = lhist[tid];
  int e = block_scan_excl(v, lds);
  int node = (p << 8) + tid;
  if (node < N_NODES) offs[node] = r0 + e;
  if (p == 0 && tid == 0) offs[N_NODES] = E_TOT;
  lhist[tid] = e;
  __syncthreads();
  for (int i = r0 + tid; i < r1; i += 256) {
    int2 rec = swp1[i];
    unsigned key = (unsigned)rec.x;
    int pos = r0 + atomicAdd(&lhist[(key >> 16) & 255u], 1);
    swp2[pos] = make_int2((int)(key & 0xFFFFu), rec.y);
  }
}

// ---- pre-split W^T into bf16 hi/lo: wt[ch][k] = split(W[k][ch]) ----
__global__ __launch_bounds__(256) void wprep_kernel(const float* __restrict__ W1,
    const float* __restrict__ W2, u16* __restrict__ w1h, u16* __restrict__ w1l,
    u16* __restrict__ w2h, u16* __restrict__ w2l) {
  int i = blockIdx.x * 256 + threadIdx.x;
  if (i < 128 * 256) {
    int ch = i >> 8, k = i & 255;
    u16 h, l; splitbf(W1[k * 128 + ch], h, l);
    w1h[i] = h; w1l[i] = l;
  } else if (i < 128 * 256 + 128 * 128) {
    int j = i - 128 * 256;
    int ch = j >> 7, k = j & 127;
    u16 h, l; splitbf(W2[k * 128 + ch], h, l);
    w2h[j] = h; w2l[j] = l;
  }
}

// ---- split-bf16 MFMA GEMM + fused attention-coefficient epilogue ----
__global__ __launch_bounds__(256) void mfma_gemm_kernel(const float* __restrict__ A,
    const u16* __restrict__ wth, const u16* __restrict__ wtl,
    const float* __restrict__ att_s, const float* __restrict__ att_d,
    __half* __restrict__ h16, float* __restrict__ a_s, float* __restrict__ a_d,
    int M, int K) {
  __shared__ u16 Xh[128][KP], Xl[128][KP];   // [node][k]
  __shared__ u16 Gh[128][KP], Gl[128][KP];   // [ch][k]  (W^T)
  int tid  = threadIdx.x;
  int lane = tid & 63, wid = tid >> 6;
  int q = lane >> 4, r = lane & 15;
  int wm = wid >> 1, wn = wid & 1;
  int node0 = blockIdx.x * 128;
  int srow  = tid >> 1;
  int skoff = (tid & 1) << 4;

  f32x4 acc[4][4];
  #pragma unroll
  for (int i = 0; i < 4; ++i)
    #pragma unroll
    for (int j = 0; j < 4; ++j) acc[i][j] = (f32x4)0.f;

  for (int k0 = 0; k0 < K; k0 += 32) {
    int gn = node0 + srow;
    float xv[16];
    if (gn < M) {
      const float* src = A + (size_t)gn * K + k0 + skoff;
      #pragma unroll
      for (int j = 0; j < 4; ++j) {
        float4 t = *(const float4*)(src + j * 4);
        xv[j * 4 + 0] = t.x; xv[j * 4 + 1] = t.y;
        xv[j * 4 + 2] = t.z; xv[j * 4 + 3] = t.w;
      }
    } else {
      #pragma unroll
      for (int j = 0; j < 16; ++j) xv[j] = 0.f;
    }
    const u16* wsrc = wth + (size_t)srow * K + k0 + skoff;
    const u16* lsrc = wtl + (size_t)srow * K + k0 + skoff;
    short8 wh0 = *(const short8*)wsrc;
    short8 wh1 = *(const short8*)(wsrc + 8);
    short8 wl0 = *(const short8*)lsrc;
    short8 wl1 = *(const short8*)(lsrc + 8);
    __syncthreads();
    short8 xh0, xh1, xl0, xl1;
    #pragma unroll
    for (int j = 0; j < 8; ++j) {
      u16 h, l;
      splitbf(xv[j], h, l);     xh0[j] = (short)h; xl0[j] = (short)l;
      splitbf(xv[j + 8], h, l); xh1[j] = (short)h; xl1[j] = (short)l;
    }
    *(short8*)&Xh[srow][skoff]     = xh0;
    *(short8*)&Xh[srow][skoff + 8] = xh1;
    *(short8*)&Xl[srow][skoff]     = xl0;
    *(short8*)&Xl[srow][skoff + 8] = xl1;
    *(short8*)&Gh[srow][skoff]     = wh0;
    *(short8*)&Gh[srow][skoff + 8] = wh1;
    *(short8*)&Gl[srow][skoff]     = wl0;
    *(short8*)&Gl[srow][skoff + 8] = wl1;
    __syncthreads();
    short8 ah[4], al[4], bh[4], bl[4];
    #pragma unroll
    for (int mi = 0; mi < 4; ++mi) {
      int row = wm * 64 + mi * 16 + r;
      ah[mi] = *(const short8*)&Gh[row][q * 8];
      al[mi] = *(const short8*)&Gl[row][q * 8];
    }
    #pragma unroll
    for (int ni = 0; ni < 4; ++ni) {
      int row = wn * 64 + ni * 16 + r;
      bh[ni] = *(const short8*)&Xh[row][q * 8];
      bl[ni] = *(const short8*)&Xl[row][q * 8];
    }
    #pragma unroll
    for (int mi = 0; mi < 4; ++mi)
      #pragma unroll
      for (int ni = 0; ni < 4; ++ni) {
        acc[mi][ni] = __builtin_amdgcn_mfma_f32_16x16x32_bf16(ah[mi], bh[ni], acc[mi][ni], 0, 0, 0);
        acc[mi][ni] = __builtin_amdgcn_mfma_f32_16x16x32_bf16(ah[mi], bl[ni], acc[mi][ni], 0, 0, 0);
        acc[mi][ni] = __builtin_amdgcn_mfma_f32_16x16x32_bf16(al[mi], bh[ni], acc[mi][ni], 0, 0, 0);
      }
  }
  // att vectors for my 16 chs: ch = wm*64 + mi*16 + q*4 + t
  float4 sv[4], dv[4];
  #pragma unroll
  for (int mi = 0; mi < 4; ++mi) {
    sv[mi] = *(const float4*)(att_s + wm * 64 + mi * 16 + q * 4);
    dv[mi] = *(const float4*)(att_d + wm * 64 + mi * 16 + q * 4);
  }
  #pragma unroll
  for (int ni = 0; ni < 4; ++ni) {
    int node = node0 + wn * 64 + ni * 16 + r;
    if (node < M) {
      #pragma unroll
      for (int mi = 0; mi < 4; ++mi) {
        int chb = wm * 64 + mi * 16 + q * 4;
        __half hh[4];
        hh[0] = __float2half(acc[mi][ni][0]);
        hh[1] = __float2half(acc[mi][ni][1]);
        hh[2] = __float2half(acc[mi][ni][2]);
        hh[3] = __float2half(acc[mi][ni][3]);
        *(float2*)(h16 + (size_t)node * HC + chb) = *(float2*)hh;
      }
    }
    float ps0 = 0.f, pd0 = 0.f, ps1 = 0.f, pd1 = 0.f;
    #pragma unroll
    for (int mi = 0; mi < 2; ++mi)
      #pragma unroll
      for (int t = 0; t < 4; ++t) {
        float av = acc[mi][ni][t];
        ps0 += av * ((const float*)&sv[mi])[t];
        pd0 += av * ((const float*)&dv[mi])[t];
      }
    #pragma unroll
    for (int mi = 2; mi < 4; ++mi)
      #pragma unroll
      for (int t = 0; t < 4; ++t) {
        float av = acc[mi][ni][t];
        ps1 += av * ((const float*)&sv[mi])[t];
        pd1 += av * ((const float*)&dv[mi])[t];
      }
    ps0 += __shfl_xor(ps0, 16, 64); ps0 += __shfl_xor(ps0, 32, 64);
    pd0 += __shfl_xor(pd0, 16, 64); pd0 += __shfl_xor(pd0, 32, 64);
    ps1 += __shfl_xor(ps1, 16, 64); ps1 += __shfl_xor(ps1, 32, 64);
    pd1 += __shfl_xor(pd1, 16, 64); pd1 += __shfl_xor(pd1, 32, 64);
    if (q == 0 && node < M) {
      *(float2*)(a_s + (size_t)node * 4 + wm * 2) = make_float2(ps0, ps1);
      *(float2*)(a_d + (size_t)node * 4 + wm * 2) = make_float2(pd0, pd1);
    }
  }
}

// ---------------- fused alpha + softmax + aggregation, one WAVE per node ----------------
// Pass C: PAIR processing — lanes 0-31 take even edges, 32-63 odd edges; lane&31 owns
// 4 dims (ushort4 8B load = half a row); shfl_xor(32) merges halves; lanes 0-31 write
// float4. Main loop mask-free (4 pairs = 8 edges in flight).
__global__ __launch_bounds__(256) void aggregate_kernel(const __half* __restrict__ h,
    const int2* __restrict__ swp, const int* __restrict__ offs,
    const float* __restrict__ a_s, const float* __restrict__ a_d,
    const float* __restrict__ cptr, const float* __restrict__ bias,
    float* __restrict__ out, int n) {
  __shared__ float4 wals[4][TILE];
  __shared__ int    ssh[4][TILE];
  int lane = threadIdx.x & 63;
  int wv   = threadIdx.x >> 6;
  int v    = blockIdx.x * 4 + wv;
  if (v >= n) return;
  int r0  = offs[v];
  int deg = offs[v + 1] - r0;
  float4 c  = *(const float4*)cptr;
  float4 ad = *(const float4*)(a_d + (size_t)v * 4);
  float4 mx = make_float4(-INFINITY, -INFINITY, -INFINITY, -INFINITY);
  float4 sm = make_float4(0.f, 0.f, 0.f, 0.f);

  if (deg <= TILE) {
    // pass A: alpha -> LDS, track max
    for (int i = lane; i < deg; i += 64) {
      int2 sw = swp[r0 + i];
      float w = __int_as_float(sw.y);
      float4 as = *(const float4*)(a_s + (size_t)sw.x * 4);
      float4 al = alpha4(as, ad, w, c);
      wals[wv][i] = al; ssh[wv][i] = sw.x;
      mx.x = fmaxf(mx.x, al.x); mx.y = fmaxf(mx.y, al.y);
      mx.z = fmaxf(mx.z, al.z); mx.w = fmaxf(mx.w, al.w);
    }
    wave_max4(mx);
    // pass B: e = exp(alpha - m) -> LDS, track sum
    for (int i = lane; i < deg; i += 64) {
      float4 al = wals[wv][i];
      float4 e;
      e.x = expf(al.x - mx.x); e.y = expf(al.y - mx.y);
      e.z = expf(al.z - mx.z); e.w = expf(al.w - mx.w);
      wals[wv][i] = e;
      sm.x += e.x; sm.y += e.y; sm.z += e.z; sm.w += e.w;
    }
    wave_sum4(sm);
    // pass C: pair gather
    int hi  = lane >> 5;
    int l5  = lane & 31;
    int hd4 = l5 >> 3;                       // head of my 4 dims
    const __half* hb4 = h + 4 * l5;
    float a0 = 0.f, a1 = 0.f, a2 = 0.f, a3 = 0.f;
    int nfull = deg >> 1;
    int pr = 0;
    for (; pr + 4 <= nfull; pr += 4) {
      float wr[4]; int sr[4];
      #pragma unroll
      for (int j = 0; j < 4; ++j) {
        int e = 2 * (pr + j) + hi;
        sr[j] = ssh[wv][e];
        wr[j] = ((const float*)&wals[wv][e])[hd4];
      }
      ushort4 hv[4];
      #pragma unroll
      for (int j = 0; j < 4; ++j)
        hv[j] = *(const ushort4*)(hb4 + (size_t)sr[j] * HC);
      #pragma unroll
      for (int j = 0; j < 4; ++j) {
        a0 += wr[j] * h2f(hv[j].x);
        a1 += wr[j] * h2f(hv[j].y);
        a2 += wr[j] * h2f(hv[j].z);
        a3 += wr[j] * h2f(hv[j].w);
      }
    }
    for (; pr < nfull; ++pr) {
      int e = 2 * pr + hi;
      int s0 = ssh[wv][e];
      float w0 = ((const float*)&wals[wv][e])[hd4];
      ushort4 hv = *(const ushort4*)(hb4 + (size_t)s0 * HC);
      a0 += w0 * h2f(hv.x); a1 += w0 * h2f(hv.y);
      a2 += w0 * h2f(hv.z); a3 += w0 * h2f(hv.w);
    }
    if (deg & 1) {
      int e = deg - 1;
      int s0 = ssh[wv][e];
      float w0 = hi ? 0.f : ((const float*)&wals[wv][e])[hd4];
      ushort4 hv = *(const ushort4*)(hb4 + (size_t)s0 * HC);
      a0 += w0 * h2f(hv.x); a1 += w0 * h2f(hv.y);
      a2 += w0 * h2f(hv.z); a3 += w0 * h2f(hv.w);
    }
    a0 += __shfl_xor(a0, 32, 64);
    a1 += __shfl_xor(a1, 32, 64);
    a2 += __shfl_xor(a2, 32, 64);
    a3 += __shfl_xor(a3, 32, 64);
    if (hi == 0) {
      float inv = 1.0f / selh(sm, hd4);
      float4 bb = *(const float4*)(bias + 4 * l5);
      float4 rr;
      rr.x = a0 * inv + bb.x;
      rr.y = a1 * inv + bb.y;
      rr.z = a2 * inv + bb.z;
      rr.w = a3 * inv + bb.w;
      *(float4*)(out + (size_t)v * HC + 4 * l5) = rr;
    }
  } else {
    // exact streaming fallback (deg > TILE), old 2-dim/lane layout
    int head = lane >> 4;
    float2 acc = make_float2(0.f, 0.f);
    const __half* hb = h + 2 * lane;
    for (int i = lane; i < deg; i += 64) {
      int2 sw = swp[r0 + i];
      float4 as = *(const float4*)(a_s + (size_t)sw.x * 4);
      float4 al = alpha4(as, ad, __int_as_float(sw.y), c);
      mx.x = fmaxf(mx.x, al.x); mx.y = fmaxf(mx.y, al.y);
      mx.z = fmaxf(mx.z, al.z); mx.w = fmaxf(mx.w, al.w);
    }
    wave_max4(mx);
    for (int i = lane; i < deg; i += 64) {
      int2 sw = swp[r0 + i];
      float4 as = *(const float4*)(a_s + (size_t)sw.x * 4);
      float4 al = alpha4(as, ad, __int_as_float(sw.y), c);
      sm.x += expf(al.x - mx.x); sm.y += expf(al.y - mx.y);
      sm.z += expf(al.z - mx.z); sm.w += expf(al.w - mx.w);
    }
    wave_sum4(sm);
    float mxh = selh(mx, head);
    for (int i = 0; i < deg; ++i) {
      int2 sw = swp[r0 + i];
      float4 as = *(const float4*)(a_s + (size_t)sw.x * 4);
      float4 al = alpha4(as, ad, __int_as_float(sw.y), c);
      float e = expf(selh(al, head) - mxh);
      __half2 hvv = *(const __half2*)(hb + (size_t)sw.x * HC);
      acc.x += e * __low2float(hvv);
      acc.y += e * __high2float(hvv);
    }
    float inv = 1.0f / selh(sm, head);
    float2 bb = *(const float2*)(bias + 2 * lane);
    float2 rr;
    rr.x = acc.x * inv + bb.x;
    rr.y = acc.y * inv + bb.y;
    *(float2*)(out + (size_t)v * HC + 2 * lane) = rr;
  }
}

// ---------------- launcher ----------------
extern "C" void kernel_launch(void* const* d_in, const int* in_sizes, int n_in,
                              void* d_out, int out_size, void* d_ws, size_t ws_size,
                              hipStream_t stream) {
  const float* x   = (const float*)d_in[0];
  const void*  ei  = d_in[1];
  const float* ew  = (const float*)d_in[2];
  const float* W1  = (const float*)d_in[3];
  const float* as1 = (const float*)d_in[4];
  const float* ad1 = (const float*)d_in[5];
  const float* We1 = (const float*)d_in[6];
  const float* ae1 = (const float*)d_in[7];
  const float* b1  = (const float*)d_in[8];
  const float* W2  = (const float*)d_in[9];
  const float* as2 = (const float*)d_in[10];
  const float* ad2 = (const float*)d_in[11];
  const float* We2 = (const float*)d_in[12];
  const float* ae2 = (const float*)d_in[13];
  const float* b2  = (const float*)d_in[14];
  float* out = (float*)d_out;

  char* p = (char*)d_ws;
  auto alloc = [&](size_t b) { char* r = p; p += (b + 255) & ~(size_t)255; return r; };
  float*  scal     = (float*)alloc(256);
  __half* h16      = (__half*)alloc((size_t)N_NODES * HC * 2);
  float*  out1     = (float*)alloc((size_t)N_NODES * HC * 4);
  float*  a_s      = (float*)alloc((size_t)N_NODES * 4 * 4);
  float*  a_d      = (float*)alloc((size_t)N_NODES * 4 * 4);
  int*    offs     = (int*)alloc((size_t)(N_NODES + 1) * 4);
  int*    cnt      = (int*)alloc((size_t)NCH * NP * 4);
  int*    base_rel = (int*)alloc((size_t)NCH * NP * 4);
  int*    ptot     = (int*)alloc((size_t)NP * 4);
  int*    pofs     = (int*)alloc((size_t)(NP + 1) * 4);
  int2*   swp1     = (int2*)alloc((size_t)E_TOT * 8);
  int2*   swp2     = (int2*)alloc((size_t)E_TOT * 8);
  u16*    w1h      = (u16*)alloc((size_t)128 * 256 * 2);
  u16*    w1l      = (u16*)alloc((size_t)128 * 256 * 2);
  u16*    w2h      = (u16*)alloc((size_t)128 * 128 * 2);
  u16*    w2l      = (u16*)alloc((size_t)128 * 128 * 2);

  hipMemsetAsync(scal, 0, 256, stream);

  chunkhist_kernel<<<NCH, 256, 0, stream>>>(ei, ew, cnt, scal);
  colscan_kernel<<<NP, 256, 0, stream>>>(cnt, base_rel, ptot);
  pscan_prep_kernel<<<1, 256, 0, stream>>>(ptot, pofs, We1, ae1, We2, ae2, scal,
                                           1.0f / N_EDGES);
  partition_kernel<<<NCH, 256, 0, stream>>>(ei, ew, scal, base_rel, pofs, swp1);
  localsort_kernel<<<NP, 256, 0, stream>>>(swp1, pofs, offs, swp2);
  wprep_kernel<<<192, 256, 0, stream>>>(W1, W2, w1h, w1l, w2h, w2l);

  const int ggrid = (N_NODES + 127) / 128;
  const int agrid = (N_NODES + 3) / 4;
  // layer 1
  mfma_gemm_kernel<<<ggrid, 256, 0, stream>>>(x, w1h, w1l, as1, ad1, h16, a_s, a_d,
                                              N_NODES, 256);
  aggregate_kernel<<<agrid, 256, 0, stream>>>(h16, swp2, offs, a_s, a_d, scal + 4, b1,
                                              out1, N_NODES);
  // layer 2
  mfma_gemm_kernel<<<ggrid, 256, 0, stream>>>(out1, w2h, w2l, as2, ad2, h16, a_s, a_d,
                                              N_NODES, 128);
  aggregate_kernel<<<agrid, 256, 0, stream>>>(h16, swp2, offs, a_s, a_d, scal + 8, b2,
                                              out, N_NODES);
}

// Round 11
// 284.478 us; speedup vs baseline: 1.0557x; 1.0557x over previous
//
#include <hip/hip_runtime.h>
#include <hip/hip_fp16.h>

#define N_NODES 50000
#define N_EDGES 800000
#define E_TOT   850000   // N_EDGES + N_NODES self loops
#define HC 128
#define NEG_SLOPE 0.2f
#define TILE 128         // per-wave LDS edge tile (deg>TILE uses slow exact fallback)
#define KP 40            // MFMA LDS k-pitch (bf16 elems): 32 + 8 pad
#define CH 4096                              // edges per sort chunk
#define NCH ((E_TOT + CH - 1) / CH)          // 208 chunks  (< 256 required)
#define NP  ((N_NODES + 255) >> 8)           // 196 partitions of 256 dsts (< 256 required)

typedef unsigned short u16;
typedef __attribute__((ext_vector_type(8))) short short8;
typedef __attribute__((ext_vector_type(4))) float f32x4;

// ---------------- helpers ----------------
__device__ __forceinline__ int edge_get(const void* eidx, int f64, long long i) {
  return f64 ? (int)((const long long*)eidx)[i] : ((const int*)eidx)[i];
}
__device__ __forceinline__ float selh(float4 q, int head) {
  float a = (head & 1) ? q.y : q.x;
  float b = (head & 1) ? q.w : q.z;
  return (head & 2) ? b : a;
}
__device__ __forceinline__ float4 alpha4(float4 as, float4 ad, float w, float4 c) {
  float4 r;
  r.x = as.x + ad.x + w * c.x; r.x = r.x > 0.f ? r.x : NEG_SLOPE * r.x;
  r.y = as.y + ad.y + w * c.y; r.y = r.y > 0.f ? r.y : NEG_SLOPE * r.y;
  r.z = as.z + ad.z + w * c.z; r.z = r.z > 0.f ? r.z : NEG_SLOPE * r.z;
  r.w = as.w + ad.w + w * c.w; r.w = r.w > 0.f ? r.w : NEG_SLOPE * r.w;
  return r;
}
__device__ __forceinline__ void wave_max4(float4& m) {
  #pragma unroll
  for (int o = 1; o < 64; o <<= 1) {
    m.x = fmaxf(m.x, __shfl_xor(m.x, o, 64));
    m.y = fmaxf(m.y, __shfl_xor(m.y, o, 64));
    m.z = fmaxf(m.z, __shfl_xor(m.z, o, 64));
    m.w = fmaxf(m.w, __shfl_xor(m.w, o, 64));
  }
}
__device__ __forceinline__ void wave_sum4(float4& s) {
  #pragma unroll
  for (int o = 1; o < 64; o <<= 1) {
    s.x += __shfl_xor(s.x, o, 64);
    s.y += __shfl_xor(s.y, o, 64);
    s.z += __shfl_xor(s.z, o, 64);
    s.w += __shfl_xor(s.w, o, 64);
  }
}
__device__ __forceinline__ void splitbf(float v, u16& h, u16& l) {
  unsigned b = __float_as_uint(v);
  h = (u16)(b >> 16);
  float lo = v - __uint_as_float(b & 0xFFFF0000u);
  l = (u16)(__float_as_uint(lo) >> 16);
}
// 256-thread block exclusive scan (4 waves).
__device__ __forceinline__ int block_scan_excl(int val, int* lds) {
  int lane = threadIdx.x & 63, wv = threadIdx.x >> 6;
  int inc = val;
  #pragma unroll
  for (int off = 1; off < 64; off <<= 1) {
    int t = __shfl_up(inc, off, 64);
    if (lane >= off) inc += t;
  }
  if (lane == 63) lds[wv] = inc;
  __syncthreads();
  if (threadIdx.x == 0) {
    int s = 0;
    #pragma unroll
    for (int i = 0; i < 4; ++i) { int t = lds[i]; lds[i] = s; s += t; }
  }
  __syncthreads();
  return lds[wv] + inc - val;
}
// block-local int64/int32 probe (wave 0 ballot), result broadcast via LDS
__device__ __forceinline__ int local_detect(const void* eidx, int* f_sh) {
  int tid = threadIdx.x;
  if (tid < 64) {
    long long v = ((const long long*)eidx)[tid];
    int bad = (v < 0 || v >= N_NODES);
    unsigned long long anybad = __ballot(bad);
    if (tid == 0) *f_sh = (anybad == 0ull);
  }
  __syncthreads();
  return *f_sh;
}

// ---- CSR build, pass A: per-chunk partition histogram (LDS only) + ew sum ----
// scal layout (floats): [0]=sum(ew) [1]=mean [4..7]=c1 [8..11]=c2
__global__ __launch_bounds__(256) void chunkhist_kernel(const void* eidx,
    const float* __restrict__ ew, int* __restrict__ cnt, float* __restrict__ scal) {
  __shared__ int hist[NP];
  __shared__ float sh[4];
  __shared__ int f_sh;
  int c = blockIdx.x, tid = threadIdx.x;
  for (int i = tid; i < NP; i += 256) hist[i] = 0;
  int f = local_detect(eidx, &f_sh);   // includes a __syncthreads after hist init
  int i0 = c * CH, i1 = min(i0 + CH, E_TOT);
  float s = 0.f;
  for (int i = i0 + tid; i < i1; i += 256) {
    int d = (i < N_EDGES) ? edge_get(eidx, f, (long long)N_EDGES + i) : (i - N_EDGES);
    atomicAdd(&hist[d >> 8], 1);
    if (i < N_EDGES) s += ew[i];
  }
  #pragma unroll
  for (int m = 32; m >= 1; m >>= 1) s += __shfl_xor(s, m, 64);
  int lane = tid & 63, wv = tid >> 6;
  if (lane == 0) sh[wv] = s;
  __syncthreads();
  for (int i = tid; i < NP; i += 256) cnt[c * NP + i] = hist[i];
  if (tid == 0) atomicAdd(&scal[0], sh[0] + sh[1] + sh[2] + sh[3]);
}

// ---- pass B1: per-partition column scan over chunks ----
__global__ __launch_bounds__(256) void colscan_kernel(const int* __restrict__ cnt,
    int* __restrict__ base_rel, int* __restrict__ ptot) {
  __shared__ int lds[4];
  int p = blockIdx.x, c = threadIdx.x;
  int v = (c < NCH) ? cnt[c * NP + p] : 0;
  int e = block_scan_excl(v, lds);
  if (c < NCH) base_rel[c * NP + p] = e;
  if (c == 255) ptot[p] = e;
}

// ---- pass B2: scan partition totals -> pofs; fold in prep constants ----
__global__ __launch_bounds__(256) void pscan_prep_kernel(const int* __restrict__ ptot,
    int* __restrict__ pofs, const float* __restrict__ We1, const float* __restrict__ ae1,
    const float* __restrict__ We2, const float* __restrict__ ae2,
    float* __restrict__ scal, float inv_e) {
  __shared__ int lds[4];
  int t = threadIdx.x;
  int v = (t < NP) ? ptot[t] : 0;
  int e = block_scan_excl(v, lds);
  if (t <= NP) pofs[t] = e;
  float p = (t < 128) ? We1[t] * ae1[t] : We2[t - 128] * ae2[t - 128];
  #pragma unroll
  for (int m = 16; m >= 1; m >>= 1) p += __shfl_xor(p, m, 32);
  if ((t & 31) == 0) {
    int hd = (t & 127) >> 5;
    if (t < 128) scal[4 + hd] = p; else scal[8 + hd] = p;
  }
  if (t == 0) scal[1] = scal[0] * inv_e;
}

// ---- pass C: partition edges (block-exclusive contiguous runs per partition) ----
// record: x = (dst<<16)|src  (N_NODES<65536), y = bits(w)
__global__ __launch_bounds__(256) void partition_kernel(const void* eidx,
    const float* __restrict__ ew, const float* __restrict__ scal,
    const int* __restrict__ base_rel, const int* __restrict__ pofs,
    int2* __restrict__ swp1) {
  __shared__ int cur[NP];
  __shared__ int f_sh;
  int c = blockIdx.x, tid = threadIdx.x;
  for (int i = tid; i < NP; i += 256) cur[i] = base_rel[c * NP + i] + pofs[i];
  int f = local_detect(eidx, &f_sh);
  float wmean = scal[1];
  int i0 = c * CH, i1 = min(i0 + CH, E_TOT);
  for (int i = i0 + tid; i < i1; i += 256) {
    int s, d; float w;
    if (i < N_EDGES) {
      s = edge_get(eidx, f, i);
      d = edge_get(eidx, f, (long long)N_EDGES + i);
      w = ew[i];
    } else {
      s = d = i - N_EDGES;
      w = wmean;
    }
    int pos = atomicAdd(&cur[d >> 8], 1);
    swp1[pos] = make_int2((int)(((unsigned)d << 16) | (unsigned)s), __float_as_int(w));
  }
}

// ---- pass D: per-partition local counting sort (one block per partition) ----
__global__ __launch_bounds__(256) void localsort_kernel(const int2* __restrict__ swp1,
    const int* __restrict__ pofs, int* __restrict__ offs, int2* __restrict__ swp2) {
  __shared__ int lhist[256];
  __shared__ int lds[4];
  int p = blockIdx.x, tid = threadIdx.x;
  int r0 = pofs[p], r1 = pofs[p + 1];
  lhist[tid] = 0;
  __syncthreads();
  for (int i = r0 + tid; i < r1; i += 256) {
    unsigned key = (unsigned)swp1[i].x;
    atomicAdd(&lhist[(key >> 16) & 255u], 1);
  }
  __syncthreads();
  int v = lhist[tid];
  int e = block_scan_excl(v, lds);
  int node = (p << 8) + tid;
  if (node < N_NODES) offs[node] = r0 + e;
  if (p == 0 && tid == 0) offs[N_NODES] = E_TOT;
  lhist[tid] = e;
  __syncthreads();
  for (int i = r0 + tid; i < r1; i += 256) {
    int2 rec = swp1[i];
    unsigned key = (unsigned)rec.x;
    int pos = r0 + atomicAdd(&lhist[(key >> 16) & 255u], 1);
    swp2[pos] = make_int2((int)(key & 0xFFFFu), rec.y);
  }
}

// ---- pre-split W^T into bf16 hi/lo: wt[ch][k] = split(W[k][ch]) ----
__global__ __launch_bounds__(256) void wprep_kernel(const float* __restrict__ W1,
    const float* __restrict__ W2, u16* __restrict__ w1h, u16* __restrict__ w1l,
    u16* __restrict__ w2h, u16* __restrict__ w2l) {
  int i = blockIdx.x * 256 + threadIdx.x;
  if (i < 128 * 256) {
    int ch = i >> 8, k = i & 255;
    u16 h, l; splitbf(W1[k * 128 + ch], h, l);
    w1h[i] = h; w1l[i] = l;
  } else if (i < 128 * 256 + 128 * 128) {
    int j = i - 128 * 256;
    int ch = j >> 7, k = j & 127;
    u16 h, l; splitbf(W2[k * 128 + ch], h, l);
    w2h[j] = h; w2l[j] = l;
  }
}

// ---- split-bf16 MFMA GEMM + fused attention-coefficient epilogue ----
__global__ __launch_bounds__(256) void mfma_gemm_kernel(const float* __restrict__ A,
    const u16* __restrict__ wth, const u16* __restrict__ wtl,
    const float* __restrict__ att_s, const float* __restrict__ att_d,
    __half* __restrict__ h16, float* __restrict__ a_s, float* __restrict__ a_d,
    int M, int K) {
  __shared__ u16 Xh[128][KP], Xl[128][KP];   // [node][k]
  __shared__ u16 Gh[128][KP], Gl[128][KP];   // [ch][k]  (W^T)
  int tid  = threadIdx.x;
  int lane = tid & 63, wid = tid >> 6;
  int q = lane >> 4, r = lane & 15;
  int wm = wid >> 1, wn = wid & 1;
  int node0 = blockIdx.x * 128;
  int srow  = tid >> 1;
  int skoff = (tid & 1) << 4;

  f32x4 acc[4][4];
  #pragma unroll
  for (int i = 0; i < 4; ++i)
    #pragma unroll
    for (int j = 0; j < 4; ++j) acc[i][j] = (f32x4)0.f;

  for (int k0 = 0; k0 < K; k0 += 32) {
    int gn = node0 + srow;
    float xv[16];
    if (gn < M) {
      const float* src = A + (size_t)gn * K + k0 + skoff;
      #pragma unroll
      for (int j = 0; j < 4; ++j) {
        float4 t = *(const float4*)(src + j * 4);
        xv[j * 4 + 0] = t.x; xv[j * 4 + 1] = t.y;
        xv[j * 4 + 2] = t.z; xv[j * 4 + 3] = t.w;
      }
    } else {
      #pragma unroll
      for (int j = 0; j < 16; ++j) xv[j] = 0.f;
    }
    const u16* wsrc = wth + (size_t)srow * K + k0 + skoff;
    const u16* lsrc = wtl + (size_t)srow * K + k0 + skoff;
    short8 wh0 = *(const short8*)wsrc;
    short8 wh1 = *(const short8*)(wsrc + 8);
    short8 wl0 = *(const short8*)lsrc;
    short8 wl1 = *(const short8*)(lsrc + 8);
    __syncthreads();
    short8 xh0, xh1, xl0, xl1;
    #pragma unroll
    for (int j = 0; j < 8; ++j) {
      u16 h, l;
      splitbf(xv[j], h, l);     xh0[j] = (short)h; xl0[j] = (short)l;
      splitbf(xv[j + 8], h, l); xh1[j] = (short)h; xl1[j] = (short)l;
    }
    *(short8*)&Xh[srow][skoff]     = xh0;
    *(short8*)&Xh[srow][skoff + 8] = xh1;
    *(short8*)&Xl[srow][skoff]     = xl0;
    *(short8*)&Xl[srow][skoff + 8] = xl1;
    *(short8*)&Gh[srow][skoff]     = wh0;
    *(short8*)&Gh[srow][skoff + 8] = wh1;
    *(short8*)&Gl[srow][skoff]     = wl0;
    *(short8*)&Gl[srow][skoff + 8] = wl1;
    __syncthreads();
    short8 ah[4], al[4], bh[4], bl[4];
    #pragma unroll
    for (int mi = 0; mi < 4; ++mi) {
      int row = wm * 64 + mi * 16 + r;
      ah[mi] = *(const short8*)&Gh[row][q * 8];
      al[mi] = *(const short8*)&Gl[row][q * 8];
    }
    #pragma unroll
    for (int ni = 0; ni < 4; ++ni) {
      int row = wn * 64 + ni * 16 + r;
      bh[ni] = *(const short8*)&Xh[row][q * 8];
      bl[ni] = *(const short8*)&Xl[row][q * 8];
    }
    #pragma unroll
    for (int mi = 0; mi < 4; ++mi)
      #pragma unroll
      for (int ni = 0; ni < 4; ++ni) {
        acc[mi][ni] = __builtin_amdgcn_mfma_f32_16x16x32_bf16(ah[mi], bh[ni], acc[mi][ni], 0, 0, 0);
        acc[mi][ni] = __builtin_amdgcn_mfma_f32_16x16x32_bf16(ah[mi], bl[ni], acc[mi][ni], 0, 0, 0);
        acc[mi][ni] = __builtin_amdgcn_mfma_f32_16x16x32_bf16(al[mi], bh[ni], acc[mi][ni], 0, 0, 0);
      }
  }
  // att vectors for my 16 chs: ch = wm*64 + mi*16 + q*4 + t
  float4 sv[4], dv[4];
  #pragma unroll
  for (int mi = 0; mi < 4; ++mi) {
    sv[mi] = *(const float4*)(att_s + wm * 64 + mi * 16 + q * 4);
    dv[mi] = *(const float4*)(att_d + wm * 64 + mi * 16 + q * 4);
  }
  #pragma unroll
  for (int ni = 0; ni < 4; ++ni) {
    int node = node0 + wn * 64 + ni * 16 + r;
    if (node < M) {
      #pragma unroll
      for (int mi = 0; mi < 4; ++mi) {
        int chb = wm * 64 + mi * 16 + q * 4;
        __half hh[4];
        hh[0] = __float2half(acc[mi][ni][0]);
        hh[1] = __float2half(acc[mi][ni][1]);
        hh[2] = __float2half(acc[mi][ni][2]);
        hh[3] = __float2half(acc[mi][ni][3]);
        *(float2*)(h16 + (size_t)node * HC + chb) = *(float2*)hh;
      }
    }
    float ps0 = 0.f, pd0 = 0.f, ps1 = 0.f, pd1 = 0.f;
    #pragma unroll
    for (int mi = 0; mi < 2; ++mi)
      #pragma unroll
      for (int t = 0; t < 4; ++t) {
        float av = acc[mi][ni][t];
        ps0 += av * ((const float*)&sv[mi])[t];
        pd0 += av * ((const float*)&dv[mi])[t];
      }
    #pragma unroll
    for (int mi = 2; mi < 4; ++mi)
      #pragma unroll
      for (int t = 0; t < 4; ++t) {
        float av = acc[mi][ni][t];
        ps1 += av * ((const float*)&sv[mi])[t];
        pd1 += av * ((const float*)&dv[mi])[t];
      }
    ps0 += __shfl_xor(ps0, 16, 64); ps0 += __shfl_xor(ps0, 32, 64);
    pd0 += __shfl_xor(pd0, 16, 64); pd0 += __shfl_xor(pd0, 32, 64);
    ps1 += __shfl_xor(ps1, 16, 64); ps1 += __shfl_xor(ps1, 32, 64);
    pd1 += __shfl_xor(pd1, 16, 64); pd1 += __shfl_xor(pd1, 32, 64);
    if (q == 0 && node < M) {
      *(float2*)(a_s + (size_t)node * 4 + wm * 2) = make_float2(ps0, ps1);
      *(float2*)(a_d + (size_t)node * 4 + wm * 2) = make_float2(pd0, pd1);
    }
  }
}

// ---------------- fused alpha + softmax + aggregation, one WAVE per node ----------------
// Each lane owns output dims (2*lane, 2*lane+1); head = lane>>4. h gathered as fp16.
// Pass C: plain batch-8 half2 gather — measured-best (R7: 49.4us, VGPR 28, occ 67%).
__global__ __launch_bounds__(256) void aggregate_kernel(const __half* __restrict__ h,
    const int2* __restrict__ swp, const int* __restrict__ offs,
    const float* __restrict__ a_s, const float* __restrict__ a_d,
    const float* __restrict__ cptr, const float* __restrict__ bias,
    float* __restrict__ out, int n) {
  __shared__ float4 wals[4][TILE];
  __shared__ int    ssh[4][TILE];
  int lane = threadIdx.x & 63;
  int wv   = threadIdx.x >> 6;
  int v    = blockIdx.x * 4 + wv;
  if (v >= n) return;
  int r0  = offs[v];
  int deg = offs[v + 1] - r0;
  float4 c  = *(const float4*)cptr;
  float4 ad = *(const float4*)(a_d + (size_t)v * 4);
  int head  = lane >> 4;
  float2 acc = make_float2(0.f, 0.f);
  const __half* hb = h + 2 * lane;
  float4 mx = make_float4(-INFINITY, -INFINITY, -INFINITY, -INFINITY);
  float4 sm = make_float4(0.f, 0.f, 0.f, 0.f);

  if (deg <= TILE) {
    // pass A: alpha -> LDS, track max
    for (int i = lane; i < deg; i += 64) {
      int2 sw = swp[r0 + i];
      float w = __int_as_float(sw.y);
      float4 as = *(const float4*)(a_s + (size_t)sw.x * 4);
      float4 al = alpha4(as, ad, w, c);
      wals[wv][i] = al; ssh[wv][i] = sw.x;
      mx.x = fmaxf(mx.x, al.x); mx.y = fmaxf(mx.y, al.y);
      mx.z = fmaxf(mx.z, al.z); mx.w = fmaxf(mx.w, al.w);
    }
    wave_max4(mx);
    // pass B: e = exp(alpha - m) -> LDS, track sum
    for (int i = lane; i < deg; i += 64) {
      float4 al = wals[wv][i];
      float4 e;
      e.x = expf(al.x - mx.x); e.y = expf(al.y - mx.y);
      e.z = expf(al.z - mx.z); e.w = expf(al.w - mx.w);
      wals[wv][i] = e;
      sm.x += e.x; sm.y += e.y; sm.z += e.z; sm.w += e.w;
    }
    wave_sum4(sm);
    // pass C: batched gather-FMA, 8 loads in flight
    int i = 0;
    for (; i + 8 <= deg; i += 8) {
      float wr[8]; int sr[8];
      #pragma unroll
      for (int j = 0; j < 8; ++j) {
        sr[j] = ssh[wv][i + j];
        wr[j] = ((const float*)&wals[wv][i + j])[head];
      }
      __half2 hv[8];
      #pragma unroll
      for (int j = 0; j < 8; ++j)
        hv[j] = *(const __half2*)(hb + (size_t)sr[j] * HC);
      #pragma unroll
      for (int j = 0; j < 8; ++j) {
        acc.x += wr[j] * __low2float(hv[j]);
        acc.y += wr[j] * __high2float(hv[j]);
      }
    }
    for (; i < deg; ++i) {
      int s0 = ssh[wv][i];
      float w0 = ((const float*)&wals[wv][i])[head];
      __half2 hvv = *(const __half2*)(hb + (size_t)s0 * HC);
      acc.x += w0 * __low2float(hvv);
      acc.y += w0 * __high2float(hvv);
    }
  } else {
    // exact streaming fallback (deg > TILE)
    for (int i = lane; i < deg; i += 64) {
      int2 sw = swp[r0 + i];
      float4 as = *(const float4*)(a_s + (size_t)sw.x * 4);
      float4 al = alpha4(as, ad, __int_as_float(sw.y), c);
      mx.x = fmaxf(mx.x, al.x); mx.y = fmaxf(mx.y, al.y);
      mx.z = fmaxf(mx.z, al.z); mx.w = fmaxf(mx.w, al.w);
    }
    wave_max4(mx);
    for (int i = lane; i < deg; i += 64) {
      int2 sw = swp[r0 + i];
      float4 as = *(const float4*)(a_s + (size_t)sw.x * 4);
      float4 al = alpha4(as, ad, __int_as_float(sw.y), c);
      sm.x += expf(al.x - mx.x); sm.y += expf(al.y - mx.y);
      sm.z += expf(al.z - mx.z); sm.w += expf(al.w - mx.w);
    }
    wave_sum4(sm);
    float mxh = selh(mx, head);
    for (int i = 0; i < deg; ++i) {
      int2 sw = swp[r0 + i];
      float4 as = *(const float4*)(a_s + (size_t)sw.x * 4);
      float4 al = alpha4(as, ad, __int_as_float(sw.y), c);
      float e = expf(selh(al, head) - mxh);
      __half2 hvv = *(const __half2*)(hb + (size_t)sw.x * HC);
      acc.x += e * __low2float(hvv);
      acc.y += e * __high2float(hvv);
    }
  }
  float inv = 1.0f / selh(sm, head);
  float2 bb = *(const float2*)(bias + 2 * lane);
  float2 r;
  r.x = acc.x * inv + bb.x;
  r.y = acc.y * inv + bb.y;
  *(float2*)(out + (size_t)v * HC + 2 * lane) = r;
}

// ---------------- launcher ----------------
extern "C" void kernel_launch(void* const* d_in, const int* in_sizes, int n_in,
                              void* d_out, int out_size, void* d_ws, size_t ws_size,
                              hipStream_t stream) {
  const float* x   = (const float*)d_in[0];
  const void*  ei  = d_in[1];
  const float* ew  = (const float*)d_in[2];
  const float* W1  = (const float*)d_in[3];
  const float* as1 = (const float*)d_in[4];
  const float* ad1 = (const float*)d_in[5];
  const float* We1 = (const float*)d_in[6];
  const float* ae1 = (const float*)d_in[7];
  const float* b1  = (const float*)d_in[8];
  const float* W2  = (const float*)d_in[9];
  const float* as2 = (const float*)d_in[10];
  const float* ad2 = (const float*)d_in[11];
  const float* We2 = (const float*)d_in[12];
  const float* ae2 = (const float*)d_in[13];
  const float* b2  = (const float*)d_in[14];
  float* out = (float*)d_out;

  char* p = (char*)d_ws;
  auto alloc = [&](size_t b) { char* r = p; p += (b + 255) & ~(size_t)255; return r; };
  float*  scal     = (float*)alloc(256);
  __half* h16      = (__half*)alloc((size_t)N_NODES * HC * 2);
  float*  out1     = (float*)alloc((size_t)N_NODES * HC * 4);
  float*  a_s      = (float*)alloc((size_t)N_NODES * 4 * 4);
  float*  a_d      = (float*)alloc((size_t)N_NODES * 4 * 4);
  int*    offs     = (int*)alloc((size_t)(N_NODES + 1) * 4);
  int*    cnt      = (int*)alloc((size_t)NCH * NP * 4);
  int*    base_rel = (int*)alloc((size_t)NCH * NP * 4);
  int*    ptot     = (int*)alloc((size_t)NP * 4);
  int*    pofs     = (int*)alloc((size_t)(NP + 1) * 4);
  int2*   swp1     = (int2*)alloc((size_t)E_TOT * 8);
  int2*   swp2     = (int2*)alloc((size_t)E_TOT * 8);
  u16*    w1h      = (u16*)alloc((size_t)128 * 256 * 2);
  u16*    w1l      = (u16*)alloc((size_t)128 * 256 * 2);
  u16*    w2h      = (u16*)alloc((size_t)128 * 128 * 2);
  u16*    w2l      = (u16*)alloc((size_t)128 * 128 * 2);

  hipMemsetAsync(scal, 0, 256, stream);

  chunkhist_kernel<<<NCH, 256, 0, stream>>>(ei, ew, cnt, scal);
  colscan_kernel<<<NP, 256, 0, stream>>>(cnt, base_rel, ptot);
  pscan_prep_kernel<<<1, 256, 0, stream>>>(ptot, pofs, We1, ae1, We2, ae2, scal,
                                           1.0f / N_EDGES);
  partition_kernel<<<NCH, 256, 0, stream>>>(ei, ew, scal, base_rel, pofs, swp1);
  localsort_kernel<<<NP, 256, 0, stream>>>(swp1, pofs, offs, swp2);
  wprep_kernel<<<192, 256, 0, stream>>>(W1, W2, w1h, w1l, w2h, w2l);

  const int ggrid = (N_NODES + 127) / 128;
  const int agrid = (N_NODES + 3) / 4;
  // layer 1
  mfma_gemm_kernel<<<ggrid, 256, 0, stream>>>(x, w1h, w1l, as1, ad1, h16, a_s, a_d,
                                              N_NODES, 256);
  aggregate_kernel<<<agrid, 256, 0, stream>>>(h16, swp2, offs, a_s, a_d, scal + 4, b1,
                                              out1, N_NODES);
  // layer 2
  mfma_gemm_kernel<<<ggrid, 256, 0, stream>>>(out1, w2h, w2l, as2, ad2, h16, a_s, a_d,
                                              N_NODES, 128);
  aggregate_kernel<<<agrid, 256, 0, stream>>>(h16, swp2, offs, a_s, a_d, scal + 8, b2,
                                              out, N_NODES);
}